// Round 8
// baseline (6173.416 us; speedup 1.0000x reference)
//
#include <hip/hip_runtime.h>
#include <math.h>

#define NEGV (-1e9f)

// ws layout (float offsets) — total ~2.6 MB
#define W5_F    0l                    // [128][128]
#define U0_F    16384l                // [128]
#define QTQR_F  16512l                // [512][8][128]
#define CQR_F   (QTQR_F + 524288l)    // [512][8]
#define SOL_F   (CQR_F + 4096l)       // [512][200]
#define CTR_F   (SOL_F + 102400l)     // 1 int
#define WS_FLOATS (CTR_F + 4l)

typedef float f32x4 __attribute__((ext_vector_type(4)));

// ---------------- cross-lane helpers ----------------
#define DPPF(x, ctrl, oldv) __int_as_float(__builtin_amdgcn_update_dpp( \
      __float_as_int(oldv), __float_as_int(x), ctrl, 0xF, 0xF, false))

__device__ __forceinline__ float wave_max(float x) {
  x = fmaxf(x, DPPF(x, 0x111, -INFINITY));
  x = fmaxf(x, DPPF(x, 0x112, -INFINITY));
  x = fmaxf(x, DPPF(x, 0x114, -INFINITY));
  x = fmaxf(x, DPPF(x, 0x118, -INFINITY));
  x = fmaxf(x, DPPF(x, 0x142, -INFINITY));
  x = fmaxf(x, DPPF(x, 0x143, -INFINITY));
  return __int_as_float(__builtin_amdgcn_readlane(__float_as_int(x), 63));
}
__device__ __forceinline__ float wave_sum(float x) {
  x = x + DPPF(x, 0x111, 0.f);
  x = x + DPPF(x, 0x112, 0.f);
  x = x + DPPF(x, 0x114, 0.f);
  x = x + DPPF(x, 0x118, 0.f);
  x = x + DPPF(x, 0x142, 0.f);
  x = x + DPPF(x, 0x143, 0.f);
  return __int_as_float(__builtin_amdgcn_readlane(__float_as_int(x), 63));
}
// sum over 4-lane quads (lanes t&3)
__device__ __forceinline__ float sum4(float x) {
  x += DPPF(x, 0xB1, 0.f);   // xor1
  x += DPPF(x, 0x4E, 0.f);   // xor2
  return x;
}
// sum over 8-lane groups (lanes t&7)
__device__ __forceinline__ float sum8(float x) {
  x += DPPF(x, 0xB1, 0.f);
  x += DPPF(x, 0x4E, 0.f);
  x += __int_as_float(__builtin_amdgcn_ds_swizzle(__float_as_int(x), 0x101F)); // xor4
  return x;
}

// ---------------- static precompute ----------------
// blocks 0..63: W5[j][o] = sum_e Wk2[e][j]*Wout[e][o];  block 64: u0 = Wq2 @ init_node
__global__ __launch_bounds__(256)
void prep_static(const float* __restrict__ Wk2, const float* __restrict__ Wout,
                 const float* __restrict__ Wq, const float* __restrict__ initn,
                 float* __restrict__ W5, float* __restrict__ u0) {
  int bid = blockIdx.x;
  if (bid < 64) {
    int g = bid * 256 + threadIdx.x;      // 16384
    int j = g >> 7, o = g & 127;
    float s = 0.f;
    for (int e = 0; e < 128; ++e) s += Wk2[e * 128 + j] * Wout[e * 128 + o];
    W5[j * 128 + o] = s;
  } else if (threadIdx.x < 128) {
    int d = threadIdx.x;
    float s = 0.f;
    for (int jj = 0; jj < 128; ++jj) s += Wq[d * 130 + 2 + jj] * initn[jj];
    u0[d] = s;
  }
}

// qtQR[b][h][j] = sum_d QR[b][h16+d]*Wk1[h16+d][j];  cQR[b][h] = QR_h . b1_h
__global__ __launch_bounds__(256)
void prep_qr(const float* __restrict__ rf, const float* __restrict__ Wq,
             const float* __restrict__ Wk1, const float* __restrict__ b1,
             float* __restrict__ qtQR, float* __restrict__ cQR) {
  long g = (long)blockIdx.x * 256 + threadIdx.x;   // 512*1024
  int b = (int)(g >> 10), h = (int)((g >> 7) & 7), j = (int)(g & 127);
  float r0 = rf[b * 2], r1 = rf[b * 2 + 1];
  float a = 0.f, c = 0.f;
  for (int d = 0; d < 16; ++d) {
    int e = h * 16 + d;
    float q = Wq[e * 130] * r0 + Wq[e * 130 + 1] * r1;
    a += q * Wk1[e * 128 + j];
    c += q * b1[e];
  }
  qtQR[g] = a;
  if (j == 0) cQR[b * 8 + h] = c;
}

__global__ void init_ctr(int* __restrict__ c) { *c = 0; }

// ---------------- decode: emb-resident, zero persistent arrays ----------------
__global__ __attribute__((amdgpu_flat_work_group_size(1024, 1024)))
void decode(const float* __restrict__ emb, const float* __restrict__ Wq,
            const float* __restrict__ Wk1, const float* __restrict__ Wv,
            const float* __restrict__ W5g, const float* __restrict__ b1g,
            const float* __restrict__ u0g, const float* __restrict__ qtQRg,
            const float* __restrict__ cQRg, int* __restrict__ ctr,
            float* __restrict__ sol, float* __restrict__ out) {
  __shared__ __align__(16) float embL[200 * 132];   // [n][j] pad 132
  __shared__ __align__(16) float sa[200 * 8];       // scores then attn, [n][h]
  __shared__ __align__(16) float ebp[8 * 8 * 128];  // partials [g][h][j]
  __shared__ __align__(16) float qtL[8 * 128];
  __shared__ __align__(16) float qtQRL[8 * 128];
  __shared__ __align__(16) float uL[128];
  __shared__ __align__(16) float yL[128];
  __shared__ __align__(16) float mhal[128];
  __shared__ float lg[200];
  __shared__ float b1L[128];
  __shared__ float cQRL[8];
  __shared__ float cL[8];
  __shared__ int bci, bsel;

  const int t = threadIdx.x;
  const int lane = t & 63, wave = t >> 6;
  const int n4 = t >> 2, j4 = t & 3;     // P3/P8: t<800
  const int d8 = t >> 3, q8 = t & 7;     // P1/P6/P7: 128 outputs x 8
  const int h7 = t >> 7, j7 = t & 127;   // P2/P5: 8 groups x 128

  for (;;) {
    if (t == 0) bsel = atomicAdd(ctr, 1);
    __syncthreads();
    const int b = bsel;
    if (b >= 512) break;

    // claim setup
    for (int p = 0; p < 25; ++p) {
      int f = p * 1024 + t;
      int n = f >> 7, j = f & 127;
      embL[n * 132 + j] = emb[((long)b * 200 + n) * 128 + j];
    }
    qtQRL[t & 1023] = qtQRg[(long)b * 1024 + t];
    if (t < 128) { uL[t] = u0g[t]; b1L[t] = b1g[t]; }
    if (t < 8) cQRL[t] = cQRg[b * 8 + t];

    bool cm = false;           // node n4 visited (t<800)
    bool live = true, picked0 = false;
    float llsum = 0.f, chose = 0.f;
    __syncthreads();

    for (int st = 0; st < 200; ++st) {
      // ---- P2: qt[h][j] = qtQR + Wk1_h^T u_h ;  cL[h] = cQR + u_h.b1_h ----
      {
        float a = qtQRL[h7 * 128 + j7];
        #pragma unroll
        for (int d = 0; d < 16; ++d)
          a += Wk1[(h7 * 16 + d) * 128 + j7] * uL[h7 * 16 + d];
        qtL[h7 * 128 + j7] = a;
        if (t < 8) {
          float c = cQRL[t];
          #pragma unroll
          for (int d = 0; d < 16; ++d) c += uL[t * 16 + d] * b1L[t * 16 + d];
          cL[t] = c;
        }
      }
      __syncthreads();

      // ---- P3: scores -> sa[n][h]  (masked, pre-softmax) ----
      if (t < 800) {
        float acc[8] = {};
        #pragma unroll
        for (int c = 0; c < 8; ++c) {
          f32x4 e4 = *(const f32x4*)&embL[n4 * 132 + j4 * 32 + c * 4];
          #pragma unroll
          for (int h = 0; h < 8; ++h) {
            f32x4 q4 = *(const f32x4*)&qtL[h * 128 + j4 * 32 + c * 4];
            acc[h] += e4[0] * q4[0] + e4[1] * q4[1] + e4[2] * q4[2] + e4[3] * q4[3];
          }
        }
        #pragma unroll
        for (int h = 0; h < 8; ++h) acc[h] = sum4(acc[h]);
        if (j4 == 0) {
          #pragma unroll
          for (int h = 0; h < 8; ++h)
            sa[n4 * 8 + h] = cm ? NEGV : (acc[h] + cL[h]) * 0.25f;
        }
      }
      __syncthreads();

      // ---- P4: softmax per head (wave h), in place ----
      if (wave < 8) {
        const int h = wave;
        float sv[4];
        float mx = -INFINITY;
        #pragma unroll
        for (int k = 0; k < 4; ++k) {
          int n = lane + 64 * k;
          float s = (n < 200) ? sa[n * 8 + h] : -INFINITY;
          sv[k] = s;
          mx = fmaxf(mx, s);
        }
        float vmax = wave_max(mx);
        float ls = 0.f;
        #pragma unroll
        for (int k = 0; k < 4; ++k) { sv[k] = expf(sv[k] - vmax); ls += sv[k]; }
        ls = wave_sum(ls);
        #pragma unroll
        for (int k = 0; k < 4; ++k) {
          int n = lane + 64 * k;
          if (n < 200) sa[n * 8 + h] = sv[k] / ls;
        }
      }
      __syncthreads();

      // ---- P5: ebar partials  ebp[g][h][j] = sum_{n in g} at[h][n]*emb[n][j] ----
      float wvr[16];   // Wv prefetch for P6 (o=d8, chunk q8)
      {
        const float* wp = Wv + d8 * 128 + q8 * 16;
        #pragma unroll
        for (int c = 0; c < 4; ++c) {
          f32x4 w4 = *(const f32x4*)(wp + c * 4);
          wvr[c*4+0] = w4[0]; wvr[c*4+1] = w4[1]; wvr[c*4+2] = w4[2]; wvr[c*4+3] = w4[3];
        }
      }
      {
        float acc[8] = {};
        #pragma unroll
        for (int i = 0; i < 25; ++i) {
          int n = h7 * 25 + i;
          float e = embL[n * 132 + j7];
          f32x4 a0 = *(const f32x4*)&sa[n * 8];
          f32x4 a1 = *(const f32x4*)&sa[n * 8 + 4];
          acc[0] += a0[0] * e; acc[1] += a0[1] * e; acc[2] += a0[2] * e; acc[3] += a0[3] * e;
          acc[4] += a1[0] * e; acc[5] += a1[1] * e; acc[6] += a1[2] * e; acc[7] += a1[3] * e;
        }
        #pragma unroll
        for (int h = 0; h < 8; ++h) ebp[(h7 * 8 + h) * 128 + j7] = acc[h];
      }
      __syncthreads();

      // ---- P6: mha[o] = sum_g sum_chunk ebp[g][h(o)][.] * Wv[o][.] ----
      float w5r[16];   // W5 prefetch for P7 (j=d8, chunk q8)
      {
        const float* wp = W5g + d8 * 128 + q8 * 16;
        #pragma unroll
        for (int c = 0; c < 4; ++c) {
          f32x4 w4 = *(const f32x4*)(wp + c * 4);
          w5r[c*4+0] = w4[0]; w5r[c*4+1] = w4[1]; w5r[c*4+2] = w4[2]; w5r[c*4+3] = w4[3];
        }
      }
      {
        const int h = d8 >> 4;
        float a = 0.f;
        #pragma unroll
        for (int g = 0; g < 8; ++g) {
          const float* pb = &ebp[(g * 8 + h) * 128 + q8 * 16];
          #pragma unroll
          for (int c = 0; c < 4; ++c) {
            f32x4 e4 = *(const f32x4*)(pb + c * 4);
            a += e4[0]*wvr[c*4+0] + e4[1]*wvr[c*4+1] + e4[2]*wvr[c*4+2] + e4[3]*wvr[c*4+3];
          }
        }
        a = sum8(a);
        if (q8 == 0) mhal[d8] = a;
      }
      __syncthreads();

      // ---- P7: y[j] = sum_o W5[j][o]*mha[o] ----
      {
        float a = 0.f;
        #pragma unroll
        for (int c = 0; c < 4; ++c) {
          f32x4 m4v = *(const f32x4*)&mhal[q8 * 16 + c * 4];
          a += m4v[0]*w5r[c*4+0] + m4v[1]*w5r[c*4+1] + m4v[2]*w5r[c*4+2] + m4v[3]*w5r[c*4+3];
        }
        a = sum8(a);
        if (q8 == 0) yL[d8] = a;
      }
      __syncthreads();

      // ---- P8: logits[m] = 10*tanh((emb[m].y)/sqrt(128)), masked ----
      float wqr[16];   // Wq2 prefetch for tail u-phase (d=d8, chunk q8)
      {
        const float* wp = Wq + d8 * 130 + 2 + q8 * 16;
        #pragma unroll
        for (int i = 0; i < 16; ++i) wqr[i] = wp[i];
      }
      if (t < 800) {
        float a = 0.f;
        #pragma unroll
        for (int c = 0; c < 8; ++c) {
          f32x4 e4 = *(const f32x4*)&embL[n4 * 132 + j4 * 32 + c * 4];
          f32x4 y4 = *(const f32x4*)&yL[j4 * 32 + c * 4];
          a += e4[0]*y4[0] + e4[1]*y4[1] + e4[2]*y4[2] + e4[3]*y4[3];
        }
        a = sum4(a);
        if (j4 == 0) {
          float l = 10.f * tanhf(a / 11.313708498984761f);
          lg[n4] = cm ? NEGV : l;
        }
      }
      __syncthreads();

      // ---- P9: argmax + lse (waves 0-7, redundant) ----
      if (wave < 8) {
        float lv[4];
        float mx = -INFINITY;
        #pragma unroll
        for (int k = 0; k < 4; ++k) {
          int n = lane + 64 * k;
          lv[k] = (n < 200) ? lg[n] : -INFINITY;
          mx = fmaxf(mx, lv[k]);
        }
        float vmax = wave_max(mx);
        int bidx = -1;
        #pragma unroll
        for (int k = 0; k < 4; ++k) {
          unsigned long long bm =
              __ballot((lane + 64 * k < 200) && (lv[k] == vmax));
          if (bidx < 0 && bm != 0ull) bidx = k * 64 + (int)__builtin_ctzll(bm);
        }
        int nxt = live ? bidx : 0;
        float e = 0.f;
        #pragma unroll
        for (int k = 0; k < 4; ++k) e += expf(lv[k] - vmax);
        float se_ = wave_sum(e);
        float lse = logf(se_);
        if (t == 0) {
          chose = live ? (-lse) : ((lv[0] - vmax) - lse);
          out[2048 + (long)b * 200 + st] = (float)nxt;
          bci = nxt;
        }
      }
      __syncthreads();

      // ---- tail: bookkeeping + u for next step ----
      int nxt = bci;
      if (!live) {
        if (t == 0) llsum += chose * (float)(200 - st);
        for (int s2 = st + 1 + t; s2 < 200; s2 += 1024)
          out[2048 + (long)b * 200 + s2] = 0.f;
        break;
      }
      if (t == 0) llsum += chose;
      if (t < 800 && nxt == n4) cm = true;
      {
        float a = 0.f;
        const float* ep = embL + nxt * 132 + q8 * 16;
        #pragma unroll
        for (int i = 0; i < 16; ++i) a += wqr[i] * ep[i];
        a = sum8(a);
        if (q8 == 0) uL[d8] = a;
      }
      if (nxt == 0) { live = false; picked0 = true; }
      __syncthreads();
    }

    if (t == 0) out[1536 + b] = picked0 ? llsum : 0.f;
    if (t < 800 && j4 == 0) {
      float s = (n4 == 0) ? 1.f : ((picked0 && cm) ? 1.f : 0.f);
      sol[(long)b * 200 + n4] = s;
    }
    __syncthreads();   // protect LDS before next claim
  }
}

// ---------------- cost ----------------
__global__ __launch_bounds__(256)
void cost_kernel(const float* __restrict__ x, const float* __restrict__ rf,
                 const float* __restrict__ sol, float* __restrict__ out) {
  __shared__ float solL[256];
  __shared__ float red[8];
  const int b = blockIdx.x, t = threadIdx.x;
  solL[t] = (t < 200) ? sol[b * 200 + t] : 0.f;
  __syncthreads();
  const float* x0 = x + (long)b * 40000;
  const float* x1 = x + 20480000l + (long)b * 40000;
  float a1 = 0.f, a2 = 0.f;
  if (t < 200) {
    for (int i = 0; i < 200; ++i) {
      if (solL[i] != 0.f) {
        a1 += x0[i * 200 + t];
        a2 += x1[i * 200 + t];
      }
    }
    float w = solL[t];
    a1 *= w; a2 *= w;
  }
  #pragma unroll
  for (int off = 32; off > 0; off >>= 1) {
    a1 += __shfl_xor(a1, off);
    a2 += __shfl_xor(a2, off);
  }
  if ((t & 63) == 0) { red[(t >> 6) * 2] = a1; red[(t >> 6) * 2 + 1] = a2; }
  __syncthreads();
  if (t == 0) {
    float f1 = red[0] + red[2] + red[4] + red[6];
    float f2 = red[1] + red[3] + red[5] + red[7];
    out[b]        = -(f1 * rf[0] + f2 * rf[1]);
    out[512 + b]  = f1;
    out[1024 + b] = f2;
  }
}

extern "C" void kernel_launch(void* const* d_in, const int* in_sizes, int n_in,
                              void* d_out, int out_size, void* d_ws, size_t ws_size,
                              hipStream_t stream) {
  const float* x     = (const float*)d_in[0];
  const float* rf    = (const float*)d_in[1];
  const float* emb   = (const float*)d_in[2];
  const float* Wk1   = (const float*)d_in[4];
  const float* bk1   = (const float*)d_in[5];
  const float* Wv    = (const float*)d_in[6];
  const float* Wk2   = (const float*)d_in[7];
  const float* Wout  = (const float*)d_in[8];
  const float* Wq    = (const float*)d_in[9];
  const float* initn = (const float*)d_in[10];
  float* out = (float*)d_out;
  float* ws  = (float*)d_ws;

  if (ws_size < (size_t)WS_FLOATS * 4) return;

  float* W5b   = ws + W5_F;
  float* u0b   = ws + U0_F;
  float* qtQRb = ws + QTQR_F;
  float* cQRb  = ws + CQR_F;
  float* solb  = ws + SOL_F;
  int*   ctrb  = (int*)(ws + CTR_F);

  prep_static<<<65, 256, 0, stream>>>(Wk2, Wout, Wq, initn, W5b, u0b);
  prep_qr<<<2048, 256, 0, stream>>>(rf, Wq, Wk1, bk1, qtQRb, cQRb);
  init_ctr<<<1, 1, 0, stream>>>(ctrb);
  decode<<<256, 1024, 0, stream>>>(emb, Wq, Wk1, Wv, W5b, bk1, u0b,
                                   qtQRb, cQRb, ctrb, solb, out);
  cost_kernel<<<512, 256, 0, stream>>>(x, rf, solb, out);
}

// Round 9
// 1737.404 us; speedup vs baseline: 3.5532x; 3.5532x over previous
//
#include <hip/hip_runtime.h>
#include <math.h>

#define NEGV (-1e9f)

// ws layout (float offsets):
//   OUT [B*N][512] : cols 0..127 K1, 128..255 V, 256..383 U=K2@Wout,
//                    384..511 Qfull = QR + emb@Wq[:,2:]^T  (QR folded in GEMM)
//   M   [128][512], QR [B][128] (dead after gemm -> reused as work counter),
//   QI  [B][128], SOL [B][200]
#define OUT_F   0l
#define M_F     52428800l
#define QR_F    (M_F + 65536l)
#define QI_F    (QR_F + 65536l)
#define SOL_F   (QI_F + 65536l)
#define WS_FLOATS (SOL_F + 102400l)   // ~211 MB (known OK)

typedef float f32x4 __attribute__((ext_vector_type(4)));

// ---------------- DPP cross-lane helpers ----------------
#define DPPF(x, ctrl, oldv) __int_as_float(__builtin_amdgcn_update_dpp( \
      __float_as_int(oldv), __float_as_int(x), ctrl, 0xF, 0xF, false))

__device__ __forceinline__ float wave_max(float x) {
  x = fmaxf(x, DPPF(x, 0x111, -INFINITY));
  x = fmaxf(x, DPPF(x, 0x112, -INFINITY));
  x = fmaxf(x, DPPF(x, 0x114, -INFINITY));
  x = fmaxf(x, DPPF(x, 0x118, -INFINITY));
  x = fmaxf(x, DPPF(x, 0x142, -INFINITY));
  x = fmaxf(x, DPPF(x, 0x143, -INFINITY));
  return __int_as_float(__builtin_amdgcn_readlane(__float_as_int(x), 63));
}
__device__ __forceinline__ float wave_sum(float x) {
  x = x + DPPF(x, 0x111, 0.f);
  x = x + DPPF(x, 0x112, 0.f);
  x = x + DPPF(x, 0x114, 0.f);
  x = x + DPPF(x, 0x118, 0.f);
  x = x + DPPF(x, 0x142, 0.f);
  x = x + DPPF(x, 0x143, 0.f);
  return __int_as_float(__builtin_amdgcn_readlane(__float_as_int(x), 63));
}

// ---------------- static precompute ----------------
__global__ __launch_bounds__(256)
void build_M(const float* __restrict__ Wk1, const float* __restrict__ Wv,
             const float* __restrict__ Wk2, const float* __restrict__ Wout,
             const float* __restrict__ Wq, float* __restrict__ Mbuf) {
  int g = blockIdx.x * 256 + threadIdx.x;
  int j = g >> 9, c = g & 511;
  float val;
  if (c < 128) {
    val = Wk1[c * 128 + j];
  } else if (c < 256) {
    val = Wv[(c - 128) * 128 + j];
  } else if (c < 384) {
    int d = c - 256;
    float s = 0.f;
    for (int e = 0; e < 128; ++e) s += Wk2[e * 128 + j] * Wout[e * 128 + d];
    val = s;
  } else {
    val = Wq[(c - 384) * 130 + 2 + j];
  }
  Mbuf[j * 512 + c] = val;
}

__global__ __launch_bounds__(256)
void build_Q(const float* __restrict__ rf, const float* __restrict__ Wq,
             const float* __restrict__ initn, float* __restrict__ QR,
             float* __restrict__ QI) {
  int g = blockIdx.x * 256 + threadIdx.x;   // 65536 = 512*128
  int b = g >> 7, d = g & 127;
  float qr = Wq[d * 130 + 0] * rf[b * 2 + 0] + Wq[d * 130 + 1] * rf[b * 2 + 1];
  float qi = qr;
  for (int j = 0; j < 128; ++j) qi += Wq[d * 130 + 2 + j] * initn[j];
  QR[g] = qr;
  QI[g] = qi;
}

__global__ __launch_bounds__(256)
void gemm_static(const float* __restrict__ emb, const float* __restrict__ Mbuf,
                 const float* __restrict__ bk1, const float* __restrict__ QR,
                 float* __restrict__ OUT) {
  int bid = blockIdx.x;                 // 1600 row-tiles * 8 col-tiles
  int rt = bid >> 3, ct = bid & 7;
  int r0 = rt * 64, c0 = ct * 64;
  int t = threadIdx.x, ty = t >> 4, tx = t & 15;
  int row0 = r0 + ty * 4;
  int col  = c0 + tx * 4;
  float acc[4][4] = {};
  const float* mp = Mbuf + col;
  for (int kb = 0; kb < 32; ++kb) {
    int k = kb * 4;
    float4 b0 = *(const float4*)(mp + (long)(k + 0) * 512);
    float4 b1 = *(const float4*)(mp + (long)(k + 1) * 512);
    float4 b2 = *(const float4*)(mp + (long)(k + 2) * 512);
    float4 b3 = *(const float4*)(mp + (long)(k + 3) * 512);
    float bm[4][4] = {{b0.x,b0.y,b0.z,b0.w},{b1.x,b1.y,b1.z,b1.w},
                      {b2.x,b2.y,b2.z,b2.w},{b3.x,b3.y,b3.z,b3.w}};
    #pragma unroll
    for (int rr = 0; rr < 4; ++rr) {
      float4 a4 = *(const float4*)(emb + (long)(row0 + rr) * 128 + k);
      float av[4] = {a4.x, a4.y, a4.z, a4.w};
      #pragma unroll
      for (int i = 0; i < 4; ++i)
        #pragma unroll
        for (int cc = 0; cc < 4; ++cc)
          acc[rr][cc] += av[i] * bm[i][cc];
    }
  }
  float badd[4] = {0.f, 0.f, 0.f, 0.f};
  if (c0 < 128) {
    #pragma unroll
    for (int cc = 0; cc < 4; ++cc) badd[cc] = bk1[col + cc];
  }
  #pragma unroll
  for (int rr = 0; rr < 4; ++rr) {
    int row = row0 + rr;
    float v[4];
    #pragma unroll
    for (int cc = 0; cc < 4; ++cc) v[cc] = acc[rr][cc] + badd[cc];
    if (col >= 384) {
      int bb = row / 200;
      #pragma unroll
      for (int cc = 0; cc < 4; ++cc) v[cc] += QR[bb * 128 + (col - 384) + cc];
    }
    float4 v4; v4.x = v[0]; v4.y = v[1]; v4.z = v[2]; v4.w = v[3];
    *(float4*)(OUT + (long)row * 512 + col) = v4;
  }
}

__global__ void init_ctr(int* __restrict__ c) { *c = 0; }

// ---------------- decode: persistent work-stealing, U split regs/LDS ----------------
// Per-thread persistent state: V 25 + U-low 16 = 41 floats -> fits the 64-VGPR
// allocation (rounds 4-7: 57 floats spilled to scratch = the 7us/step chain).
// U-high 16 lives in LDS (51.2 KB, x5 column rotation -> 2 lanes/bank, free).
__global__ __attribute__((amdgpu_flat_work_group_size(1024, 1024)))
void decode(const float* __restrict__ OUT, const float* __restrict__ QI,
            int* __restrict__ ctr, float* __restrict__ sol,
            float* __restrict__ out) {
  __shared__ float k1t[25600];                 // [d][n]  102.4 KB
  __shared__ float at[1600];                   // attn [h][n]  6.4 KB
  __shared__ __align__(16) float mhal[128];
  __shared__ float lg[200];
  __shared__ float qv[128];
  __shared__ float ul[12800];                  // U-high: [m][64] swizzled, 51.2 KB
  __shared__ int   bci;
  __shared__ int   bsel;

  const int t = threadIdx.x;
  const int lane = t & 63, wave = t >> 6;
  const int o = t >> 3, q8 = t & 7;
  const int m4 = t >> 2, j4 = t & 3;

  for (;;) {
    if (t == 0) bsel = atomicAdd(ctr, 1);
    __syncthreads();
    const int b = bsel;
    if (b >= 512) break;
    const float* outb = OUT + (long)b * 200 * 512;

    // K1 -> LDS (transpose to [d][n])
    for (int k = 0; k < 25; ++k) {
      int f = k * 1024 + t;
      int n = f >> 7, d = f & 127;
      k1t[d * 200 + n] = outb[n * 512 + d];
    }
    // U-high -> LDS: ul[m][(c + 5m)&63] = U[m][(c>>4)*32 + 16 + (c&15)]
    for (int f = t; f < 12800; f += 1024) {
      int m = f >> 6, c = f & 63;
      ul[m * 64 + ((c + 5 * m) & 63)] =
          outb[m * 512 + 256 + (c >> 4) * 32 + 16 + (c & 15)];
    }
    // V: thread (o, q8) holds V[q8*25+i][o], i<25
    f32x4 vr0 = {}, vr1 = {}, vr2 = {}, vr3 = {}, vr4 = {}, vr5 = {};
    float v24;
    {
      const float* vp = outb + 128 + o;
      #pragma unroll
      for (int e = 0; e < 4; ++e) vr0[e] = vp[(q8 * 25 + e) * 512];
      #pragma unroll
      for (int e = 0; e < 4; ++e) vr1[e] = vp[(q8 * 25 + 4 + e) * 512];
      #pragma unroll
      for (int e = 0; e < 4; ++e) vr2[e] = vp[(q8 * 25 + 8 + e) * 512];
      #pragma unroll
      for (int e = 0; e < 4; ++e) vr3[e] = vp[(q8 * 25 + 12 + e) * 512];
      #pragma unroll
      for (int e = 0; e < 4; ++e) vr4[e] = vp[(q8 * 25 + 16 + e) * 512];
      #pragma unroll
      for (int e = 0; e < 4; ++e) vr5[e] = vp[(q8 * 25 + 20 + e) * 512];
      v24 = vp[(q8 * 25 + 24) * 512];
    }
    // U-low: thread (m4, j4) holds U[m4][j4*32 + i], i<16 (4 dwordx4 loads)
    f32x4 ur0 = {}, ur1 = {}, ur2 = {}, ur3 = {};
    if (t < 800) {
      const float* up = outb + m4 * 512 + 256 + j4 * 32;
      ur0 = *(const f32x4*)(up + 0);
      ur1 = *(const f32x4*)(up + 4);
      ur2 = *(const f32x4*)(up + 8);
      ur3 = *(const f32x4*)(up + 12);
    }
    if (t < 128) qv[t] = QI[b * 128 + t];   // step-0 query

    int mk = 0;        // per-lane mask bits (node = lane + 64k), waves 0-7
    bool cm = false;   // node m4 masked, threads < 800
    bool live = true, picked0 = false;
    float llsum = 0.f, chose = 0.f;

    __syncthreads();

    for (int st = 0; st < 200; ++st) {
      // ---- A: scores + softmax (wave h = head h); q in 2x8 chunks ----
      if (wave < 8) {
        float acc[4] = {};
        #pragma unroll
        for (int half = 0; half < 2; ++half) {
          float q8v[8];
          #pragma unroll
          for (int d = 0; d < 8; ++d) q8v[d] = qv[wave * 16 + half * 8 + d];
          #pragma unroll
          for (int k = 0; k < 4; ++k) {
            int n = lane + 64 * k;
            if (n < 200) {
              float a = 0.f;
              #pragma unroll
              for (int d = 0; d < 8; ++d)
                a += q8v[d] * k1t[(wave * 16 + half * 8 + d) * 200 + n];
              acc[k] += a;
            }
          }
        }
        float sv[4];
        float mx = -INFINITY;
        #pragma unroll
        for (int k = 0; k < 4; ++k) {
          int n = lane + 64 * k;
          float s = -INFINITY;
          if (n < 200) {
            s = acc[k] * 0.25f;
            if (mk & (1 << k)) s = NEGV;
          }
          sv[k] = s;
          mx = fmaxf(mx, s);
        }
        float vmax = wave_max(mx);
        float ls = 0.f;
        #pragma unroll
        for (int k = 0; k < 4; ++k) { sv[k] = expf(sv[k] - vmax); ls += sv[k]; }
        ls = wave_sum(ls);
        #pragma unroll
        for (int k = 0; k < 4; ++k) {
          int n = lane + 64 * k;
          if (n < 200) at[wave * 200 + n] = sv[k] / ls;
        }
      }
      __syncthreads();

      // ---- B: mha[o] = sum_n attn[h][n] * V[n][o] ----
      {
        const int h2 = t >> 7;
        const float* ap = at + h2 * 200 + q8 * 25;
        float a = 0.f;
        #pragma unroll
        for (int e = 0; e < 4; ++e) a += ap[e] * vr0[e];
        #pragma unroll
        for (int e = 0; e < 4; ++e) a += ap[4 + e] * vr1[e];
        #pragma unroll
        for (int e = 0; e < 4; ++e) a += ap[8 + e] * vr2[e];
        #pragma unroll
        for (int e = 0; e < 4; ++e) a += ap[12 + e] * vr3[e];
        #pragma unroll
        for (int e = 0; e < 4; ++e) a += ap[16 + e] * vr4[e];
        #pragma unroll
        for (int e = 0; e < 4; ++e) a += ap[20 + e] * vr5[e];
        a += ap[24] * v24;
        a += DPPF(a, 0xB1, 0.f);
        a += DPPF(a, 0x4E, 0.f);
        a += DPPF(a, 0x141, 0.f);
        if (q8 == 0) mhal[o] = a;
      }
      __syncthreads();

      // ---- C: logits[m] = 10*tanh((mha . U[m]) / sqrt(128)) ----
      if (t < 800) {
        const int ubase = m4 * 64;
        const int rot = 5 * m4;
        float a = 0.f;
        #pragma unroll
        for (int e = 0; e < 4; ++e) a += mhal[j4 * 32 + e] * ur0[e];
        #pragma unroll
        for (int e = 0; e < 4; ++e) a += mhal[j4 * 32 + 4 + e] * ur1[e];
        #pragma unroll
        for (int e = 0; e < 4; ++e) a += mhal[j4 * 32 + 8 + e] * ur2[e];
        #pragma unroll
        for (int e = 0; e < 4; ++e) a += mhal[j4 * 32 + 12 + e] * ur3[e];
        #pragma unroll
        for (int i = 0; i < 16; ++i)
          a += mhal[j4 * 32 + 16 + i] * ul[ubase + ((j4 * 16 + i + rot) & 63)];
        a += DPPF(a, 0xB1, 0.f);
        a += DPPF(a, 0x4E, 0.f);
        if (j4 == 0) {
          float l = 10.f * tanhf(a / 11.313708498984761f);
          lg[m4] = cm ? NEGV : l;
        }
      }
      __syncthreads();

      // ---- D: argmax -> issue q-row load -> lse (overlaps load) ----
      if (wave < 8) {
        float lv[4];
        float mx = -INFINITY;
        #pragma unroll
        for (int k = 0; k < 4; ++k) {
          int n = lane + 64 * k;
          lv[k] = (n < 200) ? lg[n] : -INFINITY;
          mx = fmaxf(mx, lv[k]);
        }
        float vmax = wave_max(mx);
        int bidx = -1;
        #pragma unroll
        for (int k = 0; k < 4; ++k) {
          unsigned long long bm =
              __ballot((lane + 64 * k < 200) && (lv[k] == vmax));
          if (bidx < 0 && bm != 0ull) bidx = k * 64 + (int)__builtin_ctzll(bm);
        }
        int nxt = live ? bidx : 0;
        if (t < 128) qv[t] = outb[(long)nxt * 512 + 384 + t];
        float e = 0.f;
        #pragma unroll
        for (int k = 0; k < 4; ++k) e += expf(lv[k] - vmax);
        float se_ = wave_sum(e);
        float lse = logf(se_);
        if (t == 0) {
          chose = live ? (-lse) : ((lv[0] - vmax) - lse);
          out[2048 + (long)b * 200 + st] = (float)nxt;
          bci = nxt;
        }
      }
      __syncthreads();

      int nxt = bci;
      if (!live) {
        if (t == 0) llsum += chose * (float)(200 - st);
        for (int s2 = st + 1 + t; s2 < 200; s2 += 1024)
          out[2048 + (long)b * 200 + s2] = 0.f;
        break;
      }
      if (t == 0) llsum += chose;
      if (wave < 8 && (nxt & 63) == lane) mk |= 1 << (nxt >> 6);
      if (t < 800 && nxt == m4) cm = true;
      if (nxt == 0) { live = false; picked0 = true; }
    }

    if (t == 0) out[1536 + b] = picked0 ? llsum : 0.f;
    if (t < 800 && j4 == 0) {
      float s = (m4 == 0) ? 1.f : ((picked0 && cm) ? 1.f : 0.f);
      sol[(long)b * 200 + m4] = s;
    }
    __syncthreads();   // protect LDS reuse before next grab
  }
}

// ---------------- cost ----------------
__global__ __launch_bounds__(256)
void cost_kernel(const float* __restrict__ x, const float* __restrict__ rf,
                 const float* __restrict__ sol, float* __restrict__ out) {
  __shared__ float solL[256];
  __shared__ float red[8];
  const int b = blockIdx.x, t = threadIdx.x;
  solL[t] = (t < 200) ? sol[b * 200 + t] : 0.f;
  __syncthreads();
  const float* x0 = x + (long)b * 40000;
  const float* x1 = x + 20480000l + (long)b * 40000;
  float a1 = 0.f, a2 = 0.f;
  if (t < 200) {
    for (int i = 0; i < 200; ++i) {
      if (solL[i] != 0.f) {
        a1 += x0[i * 200 + t];
        a2 += x1[i * 200 + t];
      }
    }
    float w = solL[t];
    a1 *= w; a2 *= w;
  }
  #pragma unroll
  for (int off = 32; off > 0; off >>= 1) {
    a1 += __shfl_xor(a1, off);
    a2 += __shfl_xor(a2, off);
  }
  if ((t & 63) == 0) { red[(t >> 6) * 2] = a1; red[(t >> 6) * 2 + 1] = a2; }
  __syncthreads();
  if (t == 0) {
    float f1 = red[0] + red[2] + red[4] + red[6];
    float f2 = red[1] + red[3] + red[5] + red[7];
    out[b]        = -(f1 * rf[0] + f2 * rf[1]);
    out[512 + b]  = f1;
    out[1024 + b] = f2;
  }
}

extern "C" void kernel_launch(void* const* d_in, const int* in_sizes, int n_in,
                              void* d_out, int out_size, void* d_ws, size_t ws_size,
                              hipStream_t stream) {
  const float* x     = (const float*)d_in[0];
  const float* rf    = (const float*)d_in[1];
  const float* emb   = (const float*)d_in[2];
  const float* Wk1   = (const float*)d_in[4];
  const float* bk1   = (const float*)d_in[5];
  const float* Wv    = (const float*)d_in[6];
  const float* Wk2   = (const float*)d_in[7];
  const float* Wout  = (const float*)d_in[8];
  const float* Wq    = (const float*)d_in[9];
  const float* initn = (const float*)d_in[10];
  float* out = (float*)d_out;
  float* ws  = (float*)d_ws;

  if (ws_size < (size_t)WS_FLOATS * 4) return;

  float* OUTb = ws + OUT_F;
  float* Mb   = ws + M_F;
  float* QRb  = ws + QR_F;   // dead after gemm; first 4 bytes reused as counter
  float* QIb  = ws + QI_F;
  float* solb = ws + SOL_F;

  build_M<<<256, 256, 0, stream>>>(Wk1, Wv, Wk2, Wout, Wq, Mb);
  build_Q<<<256, 256, 0, stream>>>(rf, Wq, initn, QRb, QIb);
  gemm_static<<<12800, 256, 0, stream>>>(emb, Mb, bk1, QRb, OUTb);
  init_ctr<<<1, 1, 0, stream>>>((int*)QRb);
  decode<<<256, 1024, 0, stream>>>(OUTb, QIb, (int*)QRb, solb, out);
  cost_kernel<<<512, 256, 0, stream>>>(x, rf, solb, out);
}